// Round 7
// baseline (957.677 us; speedup 1.0000x reference)
//
#include <hip/hip_runtime.h>

#define FEAT 14
#define ROLE_DIM 16
#define IDX_DIM 8
#define IN_DIM 38       // 14 + 16 + 8
#define HID 128
#define IDX_VOCAB 1024
#define TILE 32
#define SCAN_C 2048     // counts per scan block (256 threads x 8)
#define BIN_CAP 8192    // staged entries per 256-node bin (avg ~5.1k, never overflows)

typedef __attribute__((ext_vector_type(8))) short short8;
typedef __attribute__((ext_vector_type(4))) float f32x4;

// bf16 round-to-nearest-even pack
__device__ __forceinline__ ushort f2bf(float f) {
    uint u = __float_as_uint(f);
    return (ushort)((u + 0x7FFFu + ((u >> 16) & 1u)) >> 16);
}
__device__ __forceinline__ float bf2f(ushort h) {
    return __uint_as_float((uint)h << 16);
}

// ---------------------------------------------------------------------------
// Prep: bf16 + transpose of the 4 weight matrices.
// ---------------------------------------------------------------------------
__global__ void k_prep(const float* __restrict__ W1, const float* __restrict__ W2,
                       const float* __restrict__ M1, const float* __restrict__ M2,
                       ushort* __restrict__ W1t, ushort* __restrict__ W2t,
                       ushort* __restrict__ M1t, ushort* __restrict__ M2t)
{
    int t = blockIdx.x * 256 + threadIdx.x;
    if (t < 8192) {                    // W1t: 128 x 64
        int c = t >> 6, k = t & 63;
        W1t[t] = (k < IN_DIM) ? f2bf(W1[k * HID + c]) : (ushort)0;
    } else if (t < 24576) {            // W2t: 128 x 128
        int u = t - 8192; int c = u >> 7, k = u & 127;
        W2t[u] = f2bf(W2[k * HID + c]);
    } else if (t < 40960) {            // M1t
        int u = t - 24576; int c = u >> 7, k = u & 127;
        M1t[u] = f2bf(M1[k * HID + c]);
    } else if (t < 57344) {            // M2t
        int u = t - 40960; int c = u >> 7, k = u & 127;
        M2t[u] = f2bf(M2[k * HID + c]);
    }
}

// ---------------------------------------------------------------------------
// MFMA MLP A: embh = bf16(relu(relu(x@W1+b1)@W2+b2))
// ---------------------------------------------------------------------------
#define LDSA 32768

__global__ __launch_bounds__(256) void k_embed_mlp(
    const float* __restrict__ feat, const int* __restrict__ role_ids,
    const float* __restrict__ role_emb, const float* __restrict__ idx_emb,
    const ushort* __restrict__ W1t, const float* __restrict__ b1,
    const ushort* __restrict__ W2t, const float* __restrict__ b2,
    ushort* __restrict__ embh, int N)
{
    __shared__ char lds[49152];
    const int tid = threadIdx.x;
    const int w = tid >> 6, l = tid & 63;
    const int li = l & 15, hi = l >> 4;
    const int base = blockIdx.x * 64;

    // stage W1t (16KB) : [128 cols][64 k] -> 8 x 16B chunks per col
    for (int c = 0; c < 4; ++c) {
        int idx = c * 256 + tid;            // 0..1023 (16B chunks)
        int col = idx >> 3, ch = idx & 7;
        uint4 v = *(const uint4*)(W1t + col * 64 + ch * 8);
        *(uint4*)(lds + col * 256 + ((ch * 16) ^ ((col & 7) << 4))) = v;
    }
    // build x-tile [64 rows][64 k] bf16 at LDSA
    {
        int row = tid >> 2, kq = (tid & 3) * 16;
        int gr = base + row; if (gr >= N) gr = N - 1;
        int rid = role_ids[gr];
        float xv[16];
        #pragma unroll
        for (int j = 0; j < 16; ++j) {
            int k = kq + j;
            float v = 0.0f;
            if (k < FEAT)                 v = feat[gr * FEAT + k];
            else if (k < FEAT + ROLE_DIM) v = role_emb[rid * ROLE_DIM + (k - FEAT)];
            else if (k < IN_DIM)          v = idx_emb[(gr & (IDX_VOCAB - 1)) * IDX_DIM + (k - FEAT - ROLE_DIM)];
            xv[j] = v;
        }
        uint p[8];
        #pragma unroll
        for (int j = 0; j < 8; ++j)
            p[j] = (uint)f2bf(xv[2 * j]) | ((uint)f2bf(xv[2 * j + 1]) << 16);
        char* db = lds + LDSA + row * 256;
        int sw = (row & 7) << 4;
        *(uint4*)(db + ((kq * 2) ^ sw))      = make_uint4(p[0], p[1], p[2], p[3]);
        *(uint4*)(db + ((kq * 2 + 16) ^ sw)) = make_uint4(p[4], p[5], p[6], p[7]);
    }
    __syncthreads();

    // phase 1: K=64
    f32x4 C[8];
    #pragma unroll
    for (int ct = 0; ct < 8; ++ct) C[ct] = (f32x4){0.f, 0.f, 0.f, 0.f};
    {
        const int arow = w * 16 + li;
        const int asw = (arow & 7) << 4;
        #pragma unroll
        for (int ks = 0; ks < 2; ++ks) {
            short8 a = *(short8*)(lds + LDSA + arow * 256 + ((ks * 64 + hi * 16) ^ asw));
            #pragma unroll
            for (int ct = 0; ct < 8; ++ct) {
                int bcol = ct * 16 + li;
                short8 b = *(short8*)(lds + bcol * 256 + ((ks * 64 + hi * 16) ^ ((bcol & 7) << 4)));
                C[ct] = __builtin_amdgcn_mfma_f32_16x16x32_bf16(a, b, C[ct], 0, 0, 0);
            }
        }
    }
    __syncthreads();

    // H = relu(C+b1) bf16 -> LDSA; stage W2t (32KB)
    #pragma unroll
    for (int ct = 0; ct < 8; ++ct) {
        int col = ct * 16 + li;
        float bv = b1[col];
        #pragma unroll
        for (int r = 0; r < 4; ++r) {
            int hrow = w * 16 + hi * 4 + r;
            float h = fmaxf(C[ct][r] + bv, 0.0f);
            *(ushort*)(lds + LDSA + hrow * 256 + ((col * 2) ^ ((hrow & 7) << 4))) = f2bf(h);
        }
    }
    for (int c = 0; c < 8; ++c) {
        int idx = c * 256 + tid;            // 0..2047
        int col = idx >> 4, ch = idx & 15;
        uint4 v = *(const uint4*)(W2t + col * 128 + ch * 8);
        *(uint4*)(lds + col * 256 + ((ch * 16) ^ ((col & 7) << 4))) = v;
    }
    __syncthreads();

    // phase 2: K=128
    f32x4 C2[8];
    #pragma unroll
    for (int ct = 0; ct < 8; ++ct) C2[ct] = (f32x4){0.f, 0.f, 0.f, 0.f};
    {
        const int arow = w * 16 + li;
        const int asw = (arow & 7) << 4;
        #pragma unroll
        for (int ks = 0; ks < 4; ++ks) {
            short8 a = *(short8*)(lds + LDSA + arow * 256 + ((ks * 64 + hi * 16) ^ asw));
            #pragma unroll
            for (int ct = 0; ct < 8; ++ct) {
                int bcol = ct * 16 + li;
                short8 b = *(short8*)(lds + bcol * 256 + ((ks * 64 + hi * 16) ^ ((bcol & 7) << 4)));
                C2[ct] = __builtin_amdgcn_mfma_f32_16x16x32_bf16(a, b, C2[ct], 0, 0, 0);
            }
        }
    }

    // epilogue: embh = bf16(relu(C2+b2))
    #pragma unroll
    for (int ct = 0; ct < 8; ++ct) {
        int col = ct * 16 + li;
        float bv = b2[col];
        #pragma unroll
        for (int r = 0; r < 4; ++r) {
            int gr = base + w * 16 + hi * 4 + r;
            if (gr < N)
                embh[(size_t)gr * 128 + col] = f2bf(fmaxf(C2[ct][r] + bv, 0.0f));
        }
    }
}

// ---------------------------------------------------------------------------
// pin-weight histogram (1M random atomics)
// ---------------------------------------------------------------------------
__global__ void k_pw(const int* __restrict__ pb, const float* __restrict__ pv,
                     float* __restrict__ pw, int P)
{
    int i = blockIdx.x * blockDim.x + threadIdx.x;
    int stride = gridDim.x * blockDim.x;
    for (; i < P; i += stride)
        atomicAdd(&pw[pb[i]], pv[i]);
}

// ---------------------------------------------------------------------------
// k_bin: append each edge-direction into its node's bin (bin = node>>8).
// staged entry = (node, payload); payload = (nbr<<15)|round(w*32767).
// ---------------------------------------------------------------------------
__global__ void k_bin(const int* __restrict__ src, const int* __restrict__ dst,
                      const float* __restrict__ w, int* __restrict__ binCnt,
                      uint2* __restrict__ staged, int E)
{
    int i = blockIdx.x * blockDim.x + threadIdx.x;
    int stride = gridDim.x * blockDim.x;
    for (; i < E; i += stride) {
        int s = src[i];
        int d = dst[i];
        uint q = (uint)(w[i] * 32767.0f + 0.5f);
        int p0 = atomicAdd(&binCnt[s >> 8], 1);
        if (p0 < BIN_CAP) staged[((size_t)(s >> 8) << 13) + p0] = make_uint2((uint)s, ((uint)d << 15) | q);
        int p1 = atomicAdd(&binCnt[d >> 8], 1);
        if (p1 < BIN_CAP) staged[((size_t)(d >> 8) << 13) + p1] = make_uint2((uint)d, ((uint)s << 15) | q);
    }
}

// ---------------------------------------------------------------------------
// k_bincount: per-bin LDS histogram -> count[node] (plain store, no atomics)
// ---------------------------------------------------------------------------
__global__ __launch_bounds__(256) void k_bincount(
    const uint2* __restrict__ staged, const int* __restrict__ binCnt,
    int* __restrict__ count, int N)
{
    __shared__ int hist[256];
    const int tid = threadIdx.x;
    const int b = blockIdx.x;
    hist[tid] = 0;
    __syncthreads();
    int n = binCnt[b];
    if (n > BIN_CAP) n = BIN_CAP;
    const uint2* sp = staged + ((size_t)b << 13);
    for (int i = tid; i < n; i += 256)
        atomicAdd(&hist[sp[i].x & 255u], 1);
    __syncthreads();
    int node = (b << 8) + tid;
    if (node < N) count[node] = hist[tid];
}

// ---------------------------------------------------------------------------
// Two-level scan: k_scan1 (block sums) -> k_scan2 -> k_scan3 (write start)
// ---------------------------------------------------------------------------
__global__ __launch_bounds__(256) void k_scan1(const int* __restrict__ count,
                                               int* __restrict__ bsum, int N)
{
    __shared__ int wls[4];
    const int tid = threadIdx.x;
    const int base = blockIdx.x * SCAN_C + tid * 8;
    int s = 0;
    if (base + 8 <= N) {
        int4 a = *(const int4*)(count + base);
        int4 b = *(const int4*)(count + base + 4);
        s = a.x + a.y + a.z + a.w + b.x + b.y + b.z + b.w;
    } else {
        for (int j = 0; j < 8; ++j) {
            int i = base + j;
            if (i < N) s += count[i];
        }
    }
    #pragma unroll
    for (int m = 1; m < 64; m <<= 1) s += __shfl_xor(s, m);
    if ((tid & 63) == 0) wls[tid >> 6] = s;
    __syncthreads();
    if (tid == 0) bsum[blockIdx.x] = wls[0] + wls[1] + wls[2] + wls[3];
}

__global__ __launch_bounds__(1024) void k_scan2(const int* __restrict__ bsum,
                                                int* __restrict__ boff, int B)
{
    __shared__ int t[1024];
    const int tid = threadIdx.x;
    t[tid] = (tid < B) ? bsum[tid] : 0;
    __syncthreads();
    for (int off = 1; off < 1024; off <<= 1) {
        int v = (tid >= off) ? t[tid - off] : 0;
        __syncthreads();
        t[tid] += v;
        __syncthreads();
    }
    if (tid < B) boff[tid] = (tid == 0) ? 0 : t[tid - 1];
}

__global__ __launch_bounds__(256) void k_scan3(const int* __restrict__ count,
    const int* __restrict__ boff, int* __restrict__ start, int N)
{
    __shared__ int ts[256];
    const int tid = threadIdx.x;
    const int base = blockIdx.x * SCAN_C + tid * 8;
    int c[8];
    int s = 0;
    #pragma unroll
    for (int j = 0; j < 8; ++j) {
        int i = base + j;
        c[j] = (i < N) ? count[i] : 0;
        s += c[j];
    }
    ts[tid] = s;
    __syncthreads();
    for (int off = 1; off < 256; off <<= 1) {
        int v = (tid >= off) ? ts[tid - off] : 0;
        __syncthreads();
        ts[tid] += v;
        __syncthreads();
    }
    int run = boff[blockIdx.x] + ((tid == 0) ? 0 : ts[tid - 1]);
    #pragma unroll
    for (int j = 0; j < 8; ++j) {
        int i = base + j;
        if (i < N) {
            start[i] = run;
            run += c[j];
        }
    }
}

// ---------------------------------------------------------------------------
// k_order: per-bin, place staged payloads at exact CSR positions (LDS cursors).
// Writes land in the bin's contiguous ~20KB window -> L2-resident, low ampl.
// ---------------------------------------------------------------------------
__global__ __launch_bounds__(256) void k_order(
    const uint2* __restrict__ staged, const int* __restrict__ binCnt,
    const int* __restrict__ start, uint* __restrict__ entries, int N)
{
    __shared__ int lcur[256];
    const int tid = threadIdx.x;
    const int b = blockIdx.x;
    int node = (b << 8) + tid;
    lcur[tid] = (node < N) ? start[node] : 0;
    __syncthreads();
    int n = binCnt[b];
    if (n > BIN_CAP) n = BIN_CAP;
    const uint2* sp = staged + ((size_t)b << 13);
    for (int i = tid; i < n; i += 256) {
        uint2 e = sp[i];
        int p = atomicAdd(&lcur[e.x & 255u], 1);
        entries[p] = e.y;
    }
}

// ---------------------------------------------------------------------------
// gather: aggh = bf16( embh*pw + sum_nb embh[nb]*w )
// ---------------------------------------------------------------------------
__global__ __launch_bounds__(256) void k_gather(
    const ushort* __restrict__ embh,
    const uint* __restrict__ entries, const int* __restrict__ start,
    const int* __restrict__ count, const float* __restrict__ pw,
    ushort* __restrict__ aggh, int N)
{
    const int tid = threadIdx.x;
    const int node = blockIdx.x * TILE + (tid >> 3);
    const int cg = tid & 7;
    const int c0 = cg * 16;
    if (node >= N) return;

    float acc[16];
    {
        float pwn = pw[node];
        const uint4* r = (const uint4*)(embh + ((size_t)node << 7) + c0);
        uint4 u0 = r[0];
        uint4 u1 = r[1];
        uint uu[8] = {u0.x, u0.y, u0.z, u0.w, u1.x, u1.y, u1.z, u1.w};
        #pragma unroll
        for (int j = 0; j < 8; ++j) {
            acc[2*j]   = __uint_as_float(uu[j] << 16) * pwn;
            acc[2*j+1] = __uint_as_float(uu[j] & 0xffff0000u) * pwn;
        }
    }

    const int st  = start[node];
    const int deg = count[node];
    const uint* ep = entries + st;
    #pragma unroll 4
    for (int i = 0; i < deg; ++i) {
        uint en = ep[i];
        int nb   = (int)(en >> 15);
        float wt = (float)(en & 32767u) * (1.0f / 32767.0f);
        const uint4* r = (const uint4*)(embh + ((size_t)nb << 7) + c0);
        uint4 u0 = r[0];
        uint4 u1 = r[1];
        uint uu[8] = {u0.x, u0.y, u0.z, u0.w, u1.x, u1.y, u1.z, u1.w};
        #pragma unroll
        for (int j = 0; j < 8; ++j) {
            float lo = __uint_as_float(uu[j] << 16);
            float hi = __uint_as_float(uu[j] & 0xffff0000u);
            acc[2*j]   = fmaf(lo, wt, acc[2*j]);
            acc[2*j+1] = fmaf(hi, wt, acc[2*j+1]);
        }
    }

    uint p[8];
    #pragma unroll
    for (int j = 0; j < 8; ++j)
        p[j] = (uint)f2bf(acc[2*j]) | ((uint)f2bf(acc[2*j+1]) << 16);
    uint4* ap = (uint4*)(aggh + (size_t)node * HID + c0);
    ap[0] = make_uint4(p[0], p[1], p[2], p[3]);
    ap[1] = make_uint4(p[4], p[5], p[6], p[7]);
}

// ---------------------------------------------------------------------------
// MFMA MLP B: m = relu(aggh@M1+mb1)@M2+mb2; out = LN(embh+m); gsum partials.
// ---------------------------------------------------------------------------
#define LDSS 49152  // wsum f32[4][128] after W(32K)+A(16K)

__global__ __launch_bounds__(256) void k_msg_ln(
    const ushort* __restrict__ aggh, const ushort* __restrict__ embh,
    const ushort* __restrict__ M1t, const ushort* __restrict__ M2t,
    const float* __restrict__ mb1, const float* __restrict__ mb2,
    const float* __restrict__ ln_g, const float* __restrict__ ln_b,
    float* __restrict__ out, float* __restrict__ gsum, int N)
{
    __shared__ char lds[51200];
    const int tid = threadIdx.x;
    const int w = tid >> 6, l = tid & 63;
    const int li = l & 15, hi = l >> 4;
    const int base = blockIdx.x * 64;

    // stage M1t (32KB) + A-tile from aggh (16KB)
    for (int c = 0; c < 8; ++c) {
        int idx = c * 256 + tid;
        int col = idx >> 4, ch = idx & 15;
        uint4 v = *(const uint4*)(M1t + col * 128 + ch * 8);
        *(uint4*)(lds + col * 256 + ((ch * 16) ^ ((col & 7) << 4))) = v;
    }
    for (int c = 0; c < 4; ++c) {
        int idx = c * 256 + tid;
        int row = idx >> 4, ch = idx & 15;
        int gr = base + row; if (gr >= N) gr = N - 1;
        uint4 v = *(const uint4*)(aggh + (size_t)gr * 128 + ch * 8);
        *(uint4*)(lds + LDSA + row * 256 + ((ch * 16) ^ ((row & 7) << 4))) = v;
    }
    __syncthreads();

    // phase 1: K=128
    f32x4 C[8];
    #pragma unroll
    for (int ct = 0; ct < 8; ++ct) C[ct] = (f32x4){0.f, 0.f, 0.f, 0.f};
    {
        const int arow = w * 16 + li;
        const int asw = (arow & 7) << 4;
        #pragma unroll
        for (int ks = 0; ks < 4; ++ks) {
            short8 a = *(short8*)(lds + LDSA + arow * 256 + ((ks * 64 + hi * 16) ^ asw));
            #pragma unroll
            for (int ct = 0; ct < 8; ++ct) {
                int bcol = ct * 16 + li;
                short8 b = *(short8*)(lds + bcol * 256 + ((ks * 64 + hi * 16) ^ ((bcol & 7) << 4)));
                C[ct] = __builtin_amdgcn_mfma_f32_16x16x32_bf16(a, b, C[ct], 0, 0, 0);
            }
        }
    }
    __syncthreads();

    // H = relu(C+mb1) bf16 -> LDSA; stage M2t
    #pragma unroll
    for (int ct = 0; ct < 8; ++ct) {
        int col = ct * 16 + li;
        float bv = mb1[col];
        #pragma unroll
        for (int r = 0; r < 4; ++r) {
            int hrow = w * 16 + hi * 4 + r;
            float h = fmaxf(C[ct][r] + bv, 0.0f);
            *(ushort*)(lds + LDSA + hrow * 256 + ((col * 2) ^ ((hrow & 7) << 4))) = f2bf(h);
        }
    }
    for (int c = 0; c < 8; ++c) {
        int idx = c * 256 + tid;
        int col = idx >> 4, ch = idx & 15;
        uint4 v = *(const uint4*)(M2t + col * 128 + ch * 8);
        *(uint4*)(lds + col * 256 + ((ch * 16) ^ ((col & 7) << 4))) = v;
    }
    __syncthreads();

    // phase 2: K=128
    f32x4 C2[8];
    #pragma unroll
    for (int ct = 0; ct < 8; ++ct) C2[ct] = (f32x4){0.f, 0.f, 0.f, 0.f};
    {
        const int arow = w * 16 + li;
        const int asw = (arow & 7) << 4;
        #pragma unroll
        for (int ks = 0; ks < 4; ++ks) {
            short8 a = *(short8*)(lds + LDSA + arow * 256 + ((ks * 64 + hi * 16) ^ asw));
            #pragma unroll
            for (int ct = 0; ct < 8; ++ct) {
                int bcol = ct * 16 + li;
                short8 b = *(short8*)(lds + bcol * 256 + ((ks * 64 + hi * 16) ^ ((bcol & 7) << 4)));
                C2[ct] = __builtin_amdgcn_mfma_f32_16x16x32_bf16(a, b, C2[ct], 0, 0, 0);
            }
        }
    }

    // epilogue: y = C2 + mb2 + embh; LayerNorm per row; store; graph partials
    float y[8][4];
    #pragma unroll
    for (int ct = 0; ct < 8; ++ct) {
        int col = ct * 16 + li;
        float bv = mb2[col];
        #pragma unroll
        for (int r = 0; r < 4; ++r) {
            int gr = base + w * 16 + hi * 4 + r;
            int grc = gr < N ? gr : N - 1;
            y[ct][r] = C2[ct][r] + bv + bf2f(embh[(size_t)grc * 128 + col]);
        }
    }
    float rs[4] = {0, 0, 0, 0}, rq[4] = {0, 0, 0, 0};
    #pragma unroll
    for (int ct = 0; ct < 8; ++ct)
        #pragma unroll
        for (int r = 0; r < 4; ++r) { rs[r] += y[ct][r]; rq[r] += y[ct][r] * y[ct][r]; }
    #pragma unroll
    for (int m = 1; m < 16; m <<= 1) {
        #pragma unroll
        for (int r = 0; r < 4; ++r) {
            rs[r] += __shfl_xor(rs[r], m);
            rq[r] += __shfl_xor(rq[r], m);
        }
    }
    float mu[4], rstd[4];
    #pragma unroll
    for (int r = 0; r < 4; ++r) {
        mu[r] = rs[r] * (1.0f / HID);
        float var = rq[r] * (1.0f / HID) - mu[r] * mu[r];
        rstd[r] = rsqrtf(var + 1e-5f);
    }
    float cs[8];
    #pragma unroll
    for (int ct = 0; ct < 8; ++ct) {
        cs[ct] = 0.0f;
        int col = ct * 16 + li;
        float g = ln_g[col], bb = ln_b[col];
        #pragma unroll
        for (int r = 0; r < 4; ++r) {
            int gr = base + w * 16 + hi * 4 + r;
            float o = (y[ct][r] - mu[r]) * rstd[r] * g + bb;
            if (gr < N) {
                out[(size_t)gr * 128 + col] = o;
                cs[ct] += o;
            }
        }
    }
    #pragma unroll
    for (int m = 16; m < 64; m <<= 1) {
        #pragma unroll
        for (int ct = 0; ct < 8; ++ct) cs[ct] += __shfl_xor(cs[ct], m);
    }
    float* wsum = (float*)(lds + LDSS);
    if (hi == 0) {
        #pragma unroll
        for (int ct = 0; ct < 8; ++ct) wsum[w * 128 + ct * 16 + li] = cs[ct];
    }
    __syncthreads();
    if (tid < 128) {
        float s = wsum[tid] + wsum[128 + tid] + wsum[256 + tid] + wsum[384 + tid];
        atomicAdd(&gsum[tid], s);
    }
}

// ---------------------------------------------------------------------------
__global__ void k_graph(const float* __restrict__ gsum, float* __restrict__ out,
                        int N)
{
    int j = threadIdx.x;
    out[(size_t)N * HID + j] = gsum[j] * (1.0f / (float)N);
}

// ---------------------------------------------------------------------------
extern "C" void kernel_launch(void* const* d_in, const int* in_sizes, int n_in,
                              void* d_out, int out_size, void* d_ws, size_t ws_size,
                              hipStream_t stream)
{
    const float* feat      = (const float*)d_in[0];
    const int*   role_ids  = (const int*)  d_in[1];
    const int*   b2b_src   = (const int*)  d_in[2];
    const int*   b2b_dst   = (const int*)  d_in[3];
    const float* b2b_w     = (const float*)d_in[4];
    const int*   p2b_block = (const int*)  d_in[5];
    const float* p2b_w     = (const float*)d_in[6];
    const float* role_emb  = (const float*)d_in[7];
    const float* idx_emb   = (const float*)d_in[8];
    const float* W1        = (const float*)d_in[9];
    const float* b1        = (const float*)d_in[10];
    const float* W2        = (const float*)d_in[11];
    const float* b2        = (const float*)d_in[12];
    const float* M1        = (const float*)d_in[13];
    const float* mb1       = (const float*)d_in[14];
    const float* M2        = (const float*)d_in[15];
    const float* mb2       = (const float*)d_in[16];
    const float* ln_g      = (const float*)d_in[17];
    const float* ln_b      = (const float*)d_in[18];

    const int N = in_sizes[1];
    const int E = in_sizes[2];
    const int P = in_sizes[5];

    float* out = (float*)d_out;

    const int nbins = (N + 255) >> 8;
    const int B = (N + SCAN_C - 1) / SCAN_C;

    // workspace layout (16B aligned throughout)
    char* ws = (char*)d_ws;
    size_t embhBytes = (size_t)N * HID * sizeof(ushort);           // 25.6 MB
    size_t stagBytes = (size_t)nbins * BIN_CAP * sizeof(uint2);    // ~25.6 MB
    size_t entBytes  = (size_t)2 * E * sizeof(uint);               // 8 MB
    size_t vecBytes  = (size_t)N * sizeof(int);                    // 400 KB
    size_t binBytes  = ((size_t)nbins * sizeof(int) + 15) & ~15ull;

    ushort* embh    = (ushort*)ws;  ws += embhBytes;
    ushort* aggh    = (ushort*)ws;  ws += embhBytes;
    uint2*  staged  = (uint2*)ws;   ws += stagBytes;
    uint*   entries = (uint*)ws;    ws += entBytes;
    int*    startA  = (int*)ws;     ws += vecBytes;
    int*    count   = (int*)ws;     ws += vecBytes;
    float*  pw      = (float*)ws;   ws += vecBytes;   // zeroed
    float*  gsum    = (float*)ws;   ws += 512;        // zeroed
    int*    binCnt  = (int*)ws;     ws += binBytes;   // zeroed
    int*    bsum    = (int*)ws;     ws += 1024 * sizeof(int);
    int*    boff    = (int*)ws;     ws += 1024 * sizeof(int);
    ushort* W1t     = (ushort*)ws;  ws += 8192  * sizeof(ushort);
    ushort* W2t     = (ushort*)ws;  ws += 16384 * sizeof(ushort);
    ushort* M1t     = (ushort*)ws;  ws += 16384 * sizeof(ushort);
    ushort* M2t     = (ushort*)ws;  ws += 16384 * sizeof(ushort);

    // zero pw | gsum | binCnt (contiguous)
    hipMemsetAsync(pw, 0, vecBytes + 512 + binBytes, stream);

    const int nBlocks64 = (N + 63) / 64;

    k_prep<<<224, 256, 0, stream>>>(W1, W2, M1, M2, W1t, W2t, M1t, M2t);

    k_embed_mlp<<<nBlocks64, 256, 0, stream>>>(
        feat, role_ids, role_emb, idx_emb, W1t, b1, W2t, b2, embh, N);

    k_bin<<<2048, 256, 0, stream>>>(b2b_src, b2b_dst, b2b_w, binCnt, staged, E);

    k_pw<<<1024, 256, 0, stream>>>(p2b_block, p2b_w, pw, P);

    k_bincount<<<nbins, 256, 0, stream>>>(staged, binCnt, count, N);

    k_scan1<<<B, 256, 0, stream>>>(count, bsum, N);
    k_scan2<<<1, 1024, 0, stream>>>(bsum, boff, B);
    k_scan3<<<B, 256, 0, stream>>>(count, boff, startA, N);

    k_order<<<nbins, 256, 0, stream>>>(staged, binCnt, startA, entries, N);

    k_gather<<<(N + TILE - 1) / TILE, 256, 0, stream>>>(
        embh, entries, startA, count, pw, aggh, N);

    k_msg_ln<<<nBlocks64, 256, 0, stream>>>(
        aggh, embh, M1t, M2t, mb1, mb2, ln_g, ln_b, out, gsum, N);

    k_graph<<<1, HID, 0, stream>>>(gsum, out, N);
}

// Round 8
// 267.773 us; speedup vs baseline: 3.5765x; 3.5765x over previous
//
#include <hip/hip_runtime.h>

#define FEAT 14
#define ROLE_DIM 16
#define IDX_DIM 8
#define IN_DIM 38       // 14 + 16 + 8
#define HID 128
#define IDX_VOCAB 1024
#define BINN 128        // nodes per bin
#define BCAP 40         // staged capacity per (bin, block); lambda~10, P(>=41)~0
#define SORT_CAP 4096   // per-bin total entries ~2560 avg

typedef __attribute__((ext_vector_type(8))) short short8;
typedef __attribute__((ext_vector_type(4))) float f32x4;

// bf16 round-to-nearest-even pack
__device__ __forceinline__ ushort f2bf(float f) {
    uint u = __float_as_uint(f);
    return (ushort)((u + 0x7FFFu + ((u >> 16) & 1u)) >> 16);
}
__device__ __forceinline__ float bf2f(ushort h) {
    return __uint_as_float((uint)h << 16);
}

// ---------------------------------------------------------------------------
// Prep: bf16 + transpose of the 4 weight matrices.
// ---------------------------------------------------------------------------
__global__ void k_prep(const float* __restrict__ W1, const float* __restrict__ W2,
                       const float* __restrict__ M1, const float* __restrict__ M2,
                       ushort* __restrict__ W1t, ushort* __restrict__ W2t,
                       ushort* __restrict__ M1t, ushort* __restrict__ M2t)
{
    int t = blockIdx.x * 256 + threadIdx.x;
    if (t < 8192) {                    // W1t: 128 x 64
        int c = t >> 6, k = t & 63;
        W1t[t] = (k < IN_DIM) ? f2bf(W1[k * HID + c]) : (ushort)0;
    } else if (t < 24576) {            // W2t: 128 x 128
        int u = t - 8192; int c = u >> 7, k = u & 127;
        W2t[u] = f2bf(W2[k * HID + c]);
    } else if (t < 40960) {            // M1t
        int u = t - 24576; int c = u >> 7, k = u & 127;
        M1t[u] = f2bf(M1[k * HID + c]);
    } else if (t < 57344) {            // M2t
        int u = t - 40960; int c = u >> 7, k = u & 127;
        M2t[u] = f2bf(M2[k * HID + c]);
    }
}

// ---------------------------------------------------------------------------
// MFMA MLP A: embh = bf16(relu(relu(x@W1+b1)@W2+b2))
// ---------------------------------------------------------------------------
#define LDSA 32768

__global__ __launch_bounds__(256) void k_embed_mlp(
    const float* __restrict__ feat, const int* __restrict__ role_ids,
    const float* __restrict__ role_emb, const float* __restrict__ idx_emb,
    const ushort* __restrict__ W1t, const float* __restrict__ b1,
    const ushort* __restrict__ W2t, const float* __restrict__ b2,
    ushort* __restrict__ embh, int N)
{
    __shared__ char lds[49152];
    const int tid = threadIdx.x;
    const int w = tid >> 6, l = tid & 63;
    const int li = l & 15, hi = l >> 4;
    const int base = blockIdx.x * 64;

    // stage W1t (16KB) : [128 cols][64 k] -> 8 x 16B chunks per col
    for (int c = 0; c < 4; ++c) {
        int idx = c * 256 + tid;            // 0..1023 (16B chunks)
        int col = idx >> 3, ch = idx & 7;
        uint4 v = *(const uint4*)(W1t + col * 64 + ch * 8);
        *(uint4*)(lds + col * 256 + ((ch * 16) ^ ((col & 7) << 4))) = v;
    }
    // build x-tile [64 rows][64 k] bf16 at LDSA
    {
        int row = tid >> 2, kq = (tid & 3) * 16;
        int gr = base + row; if (gr >= N) gr = N - 1;
        int rid = role_ids[gr];
        float xv[16];
        #pragma unroll
        for (int j = 0; j < 16; ++j) {
            int k = kq + j;
            float v = 0.0f;
            if (k < FEAT)                 v = feat[gr * FEAT + k];
            else if (k < FEAT + ROLE_DIM) v = role_emb[rid * ROLE_DIM + (k - FEAT)];
            else if (k < IN_DIM)          v = idx_emb[(gr & (IDX_VOCAB - 1)) * IDX_DIM + (k - FEAT - ROLE_DIM)];
            xv[j] = v;
        }
        uint p[8];
        #pragma unroll
        for (int j = 0; j < 8; ++j)
            p[j] = (uint)f2bf(xv[2 * j]) | ((uint)f2bf(xv[2 * j + 1]) << 16);
        char* db = lds + LDSA + row * 256;
        int sw = (row & 7) << 4;
        *(uint4*)(db + ((kq * 2) ^ sw))      = make_uint4(p[0], p[1], p[2], p[3]);
        *(uint4*)(db + ((kq * 2 + 16) ^ sw)) = make_uint4(p[4], p[5], p[6], p[7]);
    }
    __syncthreads();

    // phase 1: K=64
    f32x4 C[8];
    #pragma unroll
    for (int ct = 0; ct < 8; ++ct) C[ct] = (f32x4){0.f, 0.f, 0.f, 0.f};
    {
        const int arow = w * 16 + li;
        const int asw = (arow & 7) << 4;
        #pragma unroll
        for (int ks = 0; ks < 2; ++ks) {
            short8 a = *(short8*)(lds + LDSA + arow * 256 + ((ks * 64 + hi * 16) ^ asw));
            #pragma unroll
            for (int ct = 0; ct < 8; ++ct) {
                int bcol = ct * 16 + li;
                short8 b = *(short8*)(lds + bcol * 256 + ((ks * 64 + hi * 16) ^ ((bcol & 7) << 4)));
                C[ct] = __builtin_amdgcn_mfma_f32_16x16x32_bf16(a, b, C[ct], 0, 0, 0);
            }
        }
    }
    __syncthreads();

    // H = relu(C+b1) bf16 -> LDSA; stage W2t (32KB)
    #pragma unroll
    for (int ct = 0; ct < 8; ++ct) {
        int col = ct * 16 + li;
        float bv = b1[col];
        #pragma unroll
        for (int r = 0; r < 4; ++r) {
            int hrow = w * 16 + hi * 4 + r;
            float h = fmaxf(C[ct][r] + bv, 0.0f);
            *(ushort*)(lds + LDSA + hrow * 256 + ((col * 2) ^ ((hrow & 7) << 4))) = f2bf(h);
        }
    }
    for (int c = 0; c < 8; ++c) {
        int idx = c * 256 + tid;            // 0..2047
        int col = idx >> 4, ch = idx & 15;
        uint4 v = *(const uint4*)(W2t + col * 128 + ch * 8);
        *(uint4*)(lds + col * 256 + ((ch * 16) ^ ((col & 7) << 4))) = v;
    }
    __syncthreads();

    // phase 2: K=128
    f32x4 C2[8];
    #pragma unroll
    for (int ct = 0; ct < 8; ++ct) C2[ct] = (f32x4){0.f, 0.f, 0.f, 0.f};
    {
        const int arow = w * 16 + li;
        const int asw = (arow & 7) << 4;
        #pragma unroll
        for (int ks = 0; ks < 4; ++ks) {
            short8 a = *(short8*)(lds + LDSA + arow * 256 + ((ks * 64 + hi * 16) ^ asw));
            #pragma unroll
            for (int ct = 0; ct < 8; ++ct) {
                int bcol = ct * 16 + li;
                short8 b = *(short8*)(lds + bcol * 256 + ((ks * 64 + hi * 16) ^ ((bcol & 7) << 4)));
                C2[ct] = __builtin_amdgcn_mfma_f32_16x16x32_bf16(a, b, C2[ct], 0, 0, 0);
            }
        }
    }

    // epilogue: embh = bf16(relu(C2+b2))
    #pragma unroll
    for (int ct = 0; ct < 8; ++ct) {
        int col = ct * 16 + li;
        float bv = b2[col];
        #pragma unroll
        for (int r = 0; r < 4; ++r) {
            int gr = base + w * 16 + hi * 4 + r;
            if (gr < N)
                embh[(size_t)gr * 128 + col] = f2bf(fmaxf(C2[ct][r] + bv, 0.0f));
        }
    }
}

// ---------------------------------------------------------------------------
// pin-weight histogram (1M atomics over 100K addresses — acceptable)
// ---------------------------------------------------------------------------
__global__ void k_pw(const int* __restrict__ pb, const float* __restrict__ pv,
                     float* __restrict__ pw, int P)
{
    int i = blockIdx.x * blockDim.x + threadIdx.x;
    int stride = gridDim.x * blockDim.x;
    for (; i < P; i += stride)
        atomicAdd(&pw[pb[i]], pv[i]);
}

// ---------------------------------------------------------------------------
// k_binp: private-segment binning. 256 blocks; block blk stages its edge
// chunk into staged[bin][blk][BCAP] using only LDS cursors (NO global
// atomics). cnt[blk][bin] written coalesced at the end.
// entry = (node, payload); payload = (nbr<<15)|round(w*32767).
// ---------------------------------------------------------------------------
__global__ __launch_bounds__(256) void k_binp(
    const int* __restrict__ src, const int* __restrict__ dst,
    const float* __restrict__ w, uint2* __restrict__ staged,
    int* __restrict__ cnt, int E, int nbins, int chunk)
{
    __shared__ int cur[1024];
    const int tid = threadIdx.x;
    const int blk = blockIdx.x;
    for (int i = tid; i < nbins; i += 256) cur[i] = 0;
    __syncthreads();
    int lo = blk * chunk;
    int hi = lo + chunk; if (hi > E) hi = E;
    for (int i = lo + tid; i < hi; i += 256) {
        int s = src[i], d = dst[i];
        uint q = (uint)(w[i] * 32767.0f + 0.5f);
        int bs = s >> 7;
        int ps = atomicAdd(&cur[bs], 1);
        if (ps < BCAP)
            staged[(size_t)(bs * 256 + blk) * BCAP + ps] = make_uint2((uint)s, ((uint)d << 15) | q);
        int bd = d >> 7;
        int pd = atomicAdd(&cur[bd], 1);
        if (pd < BCAP)
            staged[(size_t)(bd * 256 + blk) * BCAP + pd] = make_uint2((uint)d, ((uint)s << 15) | q);
    }
    __syncthreads();
    for (int i = tid; i < nbins; i += 256)
        cnt[blk * nbins + i] = min(cur[i], BCAP);
}

// ---------------------------------------------------------------------------
// k_agg: one block per 128-node bin. In-LDS counting sort of the bin's
// entries by node, then 8-threads/node register gather:
// aggh[n] = bf16( embh[n]*pw[n] + sum_nb embh[nb]*w ).
// Replaces count/scan/scatter/order/gather with zero global CSR traffic.
// ---------------------------------------------------------------------------
__global__ __launch_bounds__(256) void k_agg(
    const uint2* __restrict__ staged, const int* __restrict__ cnt,
    const ushort* __restrict__ embh, const float* __restrict__ pw,
    ushort* __restrict__ aggh, int N, int nbins)
{
    __shared__ int hist[BINN];
    __shared__ int startL[BINN];
    __shared__ int curL[BINN];
    __shared__ int sc[BINN];
    __shared__ uint sorted[SORT_CAP];

    const int tid = threadIdx.x;
    const int b = blockIdx.x;
    const int baseNode = b << 7;

    if (tid < BINN) hist[tid] = 0;
    __syncthreads();

    // pass 1: histogram by node-low-7-bits (thread t owns segment t)
    const int c = cnt[tid * nbins + b];
    const uint2* sp = staged + (size_t)(b * 256 + tid) * BCAP;
    for (int k = 0; k < c; ++k)
        atomicAdd(&hist[sp[k].x & (BINN - 1)], 1);
    __syncthreads();

    // exclusive scan of hist (Hillis-Steele, all threads hit barriers)
    int v = (tid < BINN) ? hist[tid] : 0;
    if (tid < BINN) sc[tid] = v;
    __syncthreads();
    for (int off = 1; off < BINN; off <<= 1) {
        int u = (tid < BINN && tid >= off) ? sc[tid - off] : 0;
        __syncthreads();
        if (tid < BINN) sc[tid] += u;
        __syncthreads();
    }
    if (tid < BINN) {
        startL[tid] = sc[tid] - v;
        curL[tid]   = sc[tid] - v;
    }
    __syncthreads();

    // pass 2: place payloads sorted by node
    for (int k = 0; k < c; ++k) {
        uint2 e = sp[k];
        int pos = atomicAdd(&curL[e.x & (BINN - 1)], 1);
        if (pos < SORT_CAP) sorted[pos] = e.y;
    }
    __syncthreads();

    // gather: 4 rounds x 32 nodes, 8 threads per node, acc in registers
    const int g  = tid >> 3;
    const int cg = tid & 7;
    const int c0 = cg * 16;
    for (int h = 0; h < 4; ++h) {
        int nl = h * 32 + g;
        int node = baseNode + nl;
        if (node < N) {
            float acc[16];
            float pwn = pw[node];
            const uint4* r = (const uint4*)(embh + ((size_t)node << 7) + c0);
            uint4 u0 = r[0], u1 = r[1];
            uint uu[8] = {u0.x, u0.y, u0.z, u0.w, u1.x, u1.y, u1.z, u1.w};
            #pragma unroll
            for (int j = 0; j < 8; ++j) {
                acc[2*j]   = __uint_as_float(uu[j] << 16) * pwn;
                acc[2*j+1] = __uint_as_float(uu[j] & 0xffff0000u) * pwn;
            }
            const int st = startL[nl], deg = hist[nl];
            #pragma unroll 4
            for (int i = 0; i < deg; ++i) {
                uint en = sorted[st + i];
                int nb   = (int)(en >> 15);
                float wt = (float)(en & 32767u) * (1.0f / 32767.0f);
                const uint4* rr = (const uint4*)(embh + ((size_t)nb << 7) + c0);
                uint4 q0 = rr[0], q1 = rr[1];
                uint qq[8] = {q0.x, q0.y, q0.z, q0.w, q1.x, q1.y, q1.z, q1.w};
                #pragma unroll
                for (int j = 0; j < 8; ++j) {
                    acc[2*j]   = fmaf(__uint_as_float(qq[j] << 16),        wt, acc[2*j]);
                    acc[2*j+1] = fmaf(__uint_as_float(qq[j] & 0xffff0000u), wt, acc[2*j+1]);
                }
            }
            uint p[8];
            #pragma unroll
            for (int j = 0; j < 8; ++j)
                p[j] = (uint)f2bf(acc[2*j]) | ((uint)f2bf(acc[2*j+1]) << 16);
            uint4* ap = (uint4*)(aggh + ((size_t)node << 7) + c0);
            ap[0] = make_uint4(p[0], p[1], p[2], p[3]);
            ap[1] = make_uint4(p[4], p[5], p[6], p[7]);
        }
    }
}

// ---------------------------------------------------------------------------
// MFMA MLP B: m = relu(aggh@M1+mb1)@M2+mb2; out = LN(embh+m); gsum partials.
// ---------------------------------------------------------------------------
#define LDSS 49152  // wsum f32[4][128] after W(32K)+A(16K)

__global__ __launch_bounds__(256) void k_msg_ln(
    const ushort* __restrict__ aggh, const ushort* __restrict__ embh,
    const ushort* __restrict__ M1t, const ushort* __restrict__ M2t,
    const float* __restrict__ mb1, const float* __restrict__ mb2,
    const float* __restrict__ ln_g, const float* __restrict__ ln_b,
    float* __restrict__ out, float* __restrict__ gsum, int N)
{
    __shared__ char lds[51200];
    const int tid = threadIdx.x;
    const int w = tid >> 6, l = tid & 63;
    const int li = l & 15, hi = l >> 4;
    const int base = blockIdx.x * 64;

    // stage M1t (32KB) + A-tile from aggh (16KB)
    for (int c = 0; c < 8; ++c) {
        int idx = c * 256 + tid;
        int col = idx >> 4, ch = idx & 15;
        uint4 v = *(const uint4*)(M1t + col * 128 + ch * 8);
        *(uint4*)(lds + col * 256 + ((ch * 16) ^ ((col & 7) << 4))) = v;
    }
    for (int c = 0; c < 4; ++c) {
        int idx = c * 256 + tid;
        int row = idx >> 4, ch = idx & 15;
        int gr = base + row; if (gr >= N) gr = N - 1;
        uint4 v = *(const uint4*)(aggh + (size_t)gr * 128 + ch * 8);
        *(uint4*)(lds + LDSA + row * 256 + ((ch * 16) ^ ((row & 7) << 4))) = v;
    }
    __syncthreads();

    // phase 1: K=128
    f32x4 C[8];
    #pragma unroll
    for (int ct = 0; ct < 8; ++ct) C[ct] = (f32x4){0.f, 0.f, 0.f, 0.f};
    {
        const int arow = w * 16 + li;
        const int asw = (arow & 7) << 4;
        #pragma unroll
        for (int ks = 0; ks < 4; ++ks) {
            short8 a = *(short8*)(lds + LDSA + arow * 256 + ((ks * 64 + hi * 16) ^ asw));
            #pragma unroll
            for (int ct = 0; ct < 8; ++ct) {
                int bcol = ct * 16 + li;
                short8 b = *(short8*)(lds + bcol * 256 + ((ks * 64 + hi * 16) ^ ((bcol & 7) << 4)));
                C[ct] = __builtin_amdgcn_mfma_f32_16x16x32_bf16(a, b, C[ct], 0, 0, 0);
            }
        }
    }
    __syncthreads();

    // H = relu(C+mb1) bf16 -> LDSA; stage M2t
    #pragma unroll
    for (int ct = 0; ct < 8; ++ct) {
        int col = ct * 16 + li;
        float bv = mb1[col];
        #pragma unroll
        for (int r = 0; r < 4; ++r) {
            int hrow = w * 16 + hi * 4 + r;
            float h = fmaxf(C[ct][r] + bv, 0.0f);
            *(ushort*)(lds + LDSA + hrow * 256 + ((col * 2) ^ ((hrow & 7) << 4))) = f2bf(h);
        }
    }
    for (int c = 0; c < 8; ++c) {
        int idx = c * 256 + tid;
        int col = idx >> 4, ch = idx & 15;
        uint4 v = *(const uint4*)(M2t + col * 128 + ch * 8);
        *(uint4*)(lds + col * 256 + ((ch * 16) ^ ((col & 7) << 4))) = v;
    }
    __syncthreads();

    // phase 2: K=128
    f32x4 C2[8];
    #pragma unroll
    for (int ct = 0; ct < 8; ++ct) C2[ct] = (f32x4){0.f, 0.f, 0.f, 0.f};
    {
        const int arow = w * 16 + li;
        const int asw = (arow & 7) << 4;
        #pragma unroll
        for (int ks = 0; ks < 4; ++ks) {
            short8 a = *(short8*)(lds + LDSA + arow * 256 + ((ks * 64 + hi * 16) ^ asw));
            #pragma unroll
            for (int ct = 0; ct < 8; ++ct) {
                int bcol = ct * 16 + li;
                short8 b = *(short8*)(lds + bcol * 256 + ((ks * 64 + hi * 16) ^ ((bcol & 7) << 4)));
                C2[ct] = __builtin_amdgcn_mfma_f32_16x16x32_bf16(a, b, C2[ct], 0, 0, 0);
            }
        }
    }

    // epilogue: y = C2 + mb2 + embh; LayerNorm per row; store; graph partials
    float y[8][4];
    #pragma unroll
    for (int ct = 0; ct < 8; ++ct) {
        int col = ct * 16 + li;
        float bv = mb2[col];
        #pragma unroll
        for (int r = 0; r < 4; ++r) {
            int gr = base + w * 16 + hi * 4 + r;
            int grc = gr < N ? gr : N - 1;
            y[ct][r] = C2[ct][r] + bv + bf2f(embh[(size_t)grc * 128 + col]);
        }
    }
    float rs[4] = {0, 0, 0, 0}, rq[4] = {0, 0, 0, 0};
    #pragma unroll
    for (int ct = 0; ct < 8; ++ct)
        #pragma unroll
        for (int r = 0; r < 4; ++r) { rs[r] += y[ct][r]; rq[r] += y[ct][r] * y[ct][r]; }
    #pragma unroll
    for (int m = 1; m < 16; m <<= 1) {
        #pragma unroll
        for (int r = 0; r < 4; ++r) {
            rs[r] += __shfl_xor(rs[r], m);
            rq[r] += __shfl_xor(rq[r], m);
        }
    }
    float mu[4], rstd[4];
    #pragma unroll
    for (int r = 0; r < 4; ++r) {
        mu[r] = rs[r] * (1.0f / HID);
        float var = rq[r] * (1.0f / HID) - mu[r] * mu[r];
        rstd[r] = rsqrtf(var + 1e-5f);
    }
    float cs[8];
    #pragma unroll
    for (int ct = 0; ct < 8; ++ct) {
        cs[ct] = 0.0f;
        int col = ct * 16 + li;
        float g = ln_g[col], bb = ln_b[col];
        #pragma unroll
        for (int r = 0; r < 4; ++r) {
            int gr = base + w * 16 + hi * 4 + r;
            float o = (y[ct][r] - mu[r]) * rstd[r] * g + bb;
            if (gr < N) {
                out[(size_t)gr * 128 + col] = o;
                cs[ct] += o;
            }
        }
    }
    #pragma unroll
    for (int m = 16; m < 64; m <<= 1) {
        #pragma unroll
        for (int ct = 0; ct < 8; ++ct) cs[ct] += __shfl_xor(cs[ct], m);
    }
    float* wsum = (float*)(lds + LDSS);
    if (hi == 0) {
        #pragma unroll
        for (int ct = 0; ct < 8; ++ct) wsum[w * 128 + ct * 16 + li] = cs[ct];
    }
    __syncthreads();
    if (tid < 128) {
        float s = wsum[tid] + wsum[128 + tid] + wsum[256 + tid] + wsum[384 + tid];
        atomicAdd(&gsum[tid], s);
    }
}

// ---------------------------------------------------------------------------
__global__ void k_graph(const float* __restrict__ gsum, float* __restrict__ out,
                        int N)
{
    int j = threadIdx.x;
    out[(size_t)N * HID + j] = gsum[j] * (1.0f / (float)N);
}

// ---------------------------------------------------------------------------
extern "C" void kernel_launch(void* const* d_in, const int* in_sizes, int n_in,
                              void* d_out, int out_size, void* d_ws, size_t ws_size,
                              hipStream_t stream)
{
    const float* feat      = (const float*)d_in[0];
    const int*   role_ids  = (const int*)  d_in[1];
    const int*   b2b_src   = (const int*)  d_in[2];
    const int*   b2b_dst   = (const int*)  d_in[3];
    const float* b2b_w     = (const float*)d_in[4];
    const int*   p2b_block = (const int*)  d_in[5];
    const float* p2b_w     = (const float*)d_in[6];
    const float* role_emb  = (const float*)d_in[7];
    const float* idx_emb   = (const float*)d_in[8];
    const float* W1        = (const float*)d_in[9];
    const float* b1        = (const float*)d_in[10];
    const float* W2        = (const float*)d_in[11];
    const float* b2        = (const float*)d_in[12];
    const float* M1        = (const float*)d_in[13];
    const float* mb1       = (const float*)d_in[14];
    const float* M2        = (const float*)d_in[15];
    const float* mb2       = (const float*)d_in[16];
    const float* ln_g      = (const float*)d_in[17];
    const float* ln_b      = (const float*)d_in[18];

    const int N = in_sizes[1];
    const int E = in_sizes[2];
    const int P = in_sizes[5];

    float* out = (float*)d_out;

    const int nbins = (N + BINN - 1) >> 7;            // 782
    const int chunk = (E + 255) / 256;

    // workspace layout (16B aligned throughout)
    char* ws = (char*)d_ws;
    size_t embhBytes = (size_t)N * HID * sizeof(ushort);              // 25.6 MB
    size_t stagBytes = (size_t)nbins * 256 * BCAP * sizeof(uint2);    // 64.1 MB
    size_t cntBytes  = (((size_t)256 * nbins * sizeof(int)) + 15) & ~15ull;
    size_t vecBytes  = (size_t)N * sizeof(float);                     // 400 KB

    ushort* embh    = (ushort*)ws;  ws += embhBytes;
    ushort* aggh    = (ushort*)ws;  ws += embhBytes;
    uint2*  staged  = (uint2*)ws;   ws += stagBytes;
    int*    cnt     = (int*)ws;     ws += cntBytes;
    float*  pw      = (float*)ws;   ws += vecBytes;   // zeroed
    float*  gsum    = (float*)ws;   ws += 512;        // zeroed
    ushort* W1t     = (ushort*)ws;  ws += 8192  * sizeof(ushort);
    ushort* W2t     = (ushort*)ws;  ws += 16384 * sizeof(ushort);
    ushort* M1t     = (ushort*)ws;  ws += 16384 * sizeof(ushort);
    ushort* M2t     = (ushort*)ws;  ws += 16384 * sizeof(ushort);

    // zero pw | gsum (contiguous)
    hipMemsetAsync(pw, 0, vecBytes + 512, stream);

    const int nBlocks64 = (N + 63) / 64;

    k_prep<<<224, 256, 0, stream>>>(W1, W2, M1, M2, W1t, W2t, M1t, M2t);

    k_embed_mlp<<<nBlocks64, 256, 0, stream>>>(
        feat, role_ids, role_emb, idx_emb, W1t, b1, W2t, b2, embh, N);

    k_binp<<<256, 256, 0, stream>>>(b2b_src, b2b_dst, b2b_w, staged, cnt,
                                    E, nbins, chunk);

    k_pw<<<1024, 256, 0, stream>>>(p2b_block, p2b_w, pw, P);

    k_agg<<<nbins, 256, 0, stream>>>(staged, cnt, embh, pw, aggh, N, nbins);

    k_msg_ln<<<nBlocks64, 256, 0, stream>>>(
        aggh, embh, M1t, M2t, mb1, mb2, ln_g, ln_b, out, gsum, N);

    k_graph<<<1, HID, 0, stream>>>(gsum, out, N);
}